// Round 1
// baseline (2567.567 us; speedup 1.0000x reference)
//
#include <hip/hip_runtime.h>
#include <hip/hip_bf16.h>

#define BATCH 131072
#define H 256
#define NBLK 8
#define NMID 3
#define MS 32            // samples per workgroup
#define RT_N 6           // (3 streams * MS) / 16 row-tiles
#define NT 256           // threads per workgroup

typedef __attribute__((ext_vector_type(8))) short short8;   // 8 bf16 = 4 VGPRs (MFMA A/B frag)
typedef __attribute__((ext_vector_type(4))) float f32x4;    // MFMA C/D frag

__device__ __forceinline__ unsigned short f2bf(float f) {
    unsigned u = __float_as_uint(f);
    u += 0x7FFFu + ((u >> 16) & 1u);          // RNE; inputs are finite, no NaN handling needed
    return (unsigned short)(u >> 16);
}
__device__ __forceinline__ float bf2f(unsigned short b) {
    return __uint_as_float(((unsigned)b) << 16);
}

// Pack Wm (NB*NMID layers of [256][256] fp32, k-major) into MFMA B-fragment order bf16:
// chunk o serves (layer, kk, ct, lane); element j is k = kk*32 + (lane>>4)*8 + j, n = ct*16 + (lane&15).
__global__ void pack_w_kernel(const float* __restrict__ Wm, unsigned short* __restrict__ Wp) {
    int o = blockIdx.x * blockDim.x + threadIdx.x;   // 24 * 8192 chunks
    if (o >= NBLK * NMID * 8192) return;
    int lane  = o & 63;
    int ct    = (o >> 6) & 15;
    int kk    = (o >> 10) & 7;
    int layer = o >> 13;
    int n  = ct * 16 + (lane & 15);
    int k0 = kk * 32 + (lane >> 4) * 8;
    const float* src = Wm + (size_t)layer * H * H;
    unsigned int w[4];
    #pragma unroll
    for (int jj = 0; jj < 4; ++jj) {
        unsigned short a = f2bf(src[(size_t)(k0 + 2*jj    ) * H + n]);
        unsigned short b = f2bf(src[(size_t)(k0 + 2*jj + 1) * H + n]);
        w[jj] = (unsigned)a | ((unsigned)b << 16);
    }
    uint4 val; val.x = w[0]; val.y = w[1]; val.z = w[2]; val.w = w[3];
    ((uint4*)Wp)[o] = val;
}

// Fused flow kernel. Each workgroup owns 32 samples through all 8 i-ResBlocks.
// LDS X buffer holds [6 row-tiles][8 kk][64 chunk-slots][8 bf16] in A-fragment order,
// with chunk-slot swizzle sigma(l) = l ^ ((l>>3)&7) (involution; kills epilogue-write bank conflicts).
__global__ __launch_bounds__(NT, 3)
void flow_kernel(const float* __restrict__ x, const float* __restrict__ v,
                 const float* __restrict__ Wi, const float* __restrict__ bi,
                 const float* __restrict__ bm, const float* __restrict__ Wo,
                 const float* __restrict__ bo,
                 const unsigned short* __restrict__ Wp,
                 float* __restrict__ out)
{
    __shared__ uint4 Xl4[RT_N * 8 * 64];     // 3072 chunks * 16B = 48 KiB
    __shared__ float zbuf[MS * 2];
    __shared__ float vbuf[MS * 2];

    unsigned short* Xs = (unsigned short*)Xl4;
    float* part = (float*)Xl4;               // layer-4 partial overlay (6 KiB, X is dead then)

    const int tid  = threadIdx.x;
    const int wave = tid >> 6;
    const int lane = tid & 63;
    const int s0   = blockIdx.x * MS;

    float dlp = 0.0f;
    if (tid < MS) {
        zbuf[tid*2+0] = x[(size_t)(s0+tid)*2+0];
        zbuf[tid*2+1] = x[(size_t)(s0+tid)*2+1];
        vbuf[tid*2+0] = v[(size_t)(s0+tid)*2+0];
        vbuf[tid*2+1] = v[(size_t)(s0+tid)*2+1];
    }
    __syncthreads();

    for (int b = 0; b < NBLK; ++b) {
        // ---------------- layer 0: 2 -> 256 (VALU), fill X in A-frag order ----------------
        const float* Wi0 = Wi + (size_t)b * 2 * H;
        const float* Wi1 = Wi0 + H;
        const float* bib = bi + (size_t)b * H;
        #pragma unroll
        for (int cc = 0; cc < (RT_N*8*64)/NT; ++cc) {
            int c  = cc * NT + tid;           // global chunk index
            int cl = c & 63;                  // stored slot within (rt,kk) group
            int kk = (c >> 6) & 7;
            int rt = c >> 9;
            int l  = cl ^ ((cl >> 3) & 7);    // serving lane (sigma involution)
            int m  = l & 15, q = l >> 4;
            int s  = ((rt & 1) << 4) | m;     // sample within wg
            int stream = rt >> 1;             // 0=h, 1=ta(e0), 2=tb(e1)
            float z0 = zbuf[s*2+0], z1 = zbuf[s*2+1];
            int nb = kk * 32 + q * 8;
            unsigned int wv[4];
            #pragma unroll
            for (int jj = 0; jj < 4; ++jj) {
                unsigned int pr = 0;
                #pragma unroll
                for (int hh = 0; hh < 2; ++hh) {
                    int n = nb + 2*jj + hh;
                    float w0 = Wi0[n], w1 = Wi1[n];
                    float pre = fmaf(z0, w0, fmaf(z1, w1, bib[n]));
                    float o;
                    if (stream == 0)      o = fmaxf(pre, 0.0f);
                    else if (stream == 1) o = (pre > 0.0f) ? w0 : 0.0f;   // (e0 @ Wi) * mask
                    else                  o = (pre > 0.0f) ? w1 : 0.0f;   // (e1 @ Wi) * mask
                    pr |= ((unsigned)f2bf(o)) << (16 * hh);
                }
                wv[jj] = pr;
            }
            uint4 pk; pk.x = wv[0]; pk.y = wv[1]; pk.z = wv[2]; pk.w = wv[3];
            Xl4[c] = pk;
        }
        __syncthreads();

        // ---------------- mid layers: 3x (256 -> 256) via MFMA ----------------
        for (int li = 0; li < NMID; ++li) {
            const int layer = b * NMID + li;
            const short8* Bp  = ((const short8*)Wp) + (size_t)layer * 8192;
            const float* bias = bm + (size_t)layer * H;

            f32x4 acc[RT_N][4];
            #pragma unroll
            for (int rt = 0; rt < RT_N; ++rt)
                #pragma unroll
                for (int ct = 0; ct < 4; ++ct)
                    acc[rt][ct] = (f32x4){0.f, 0.f, 0.f, 0.f};

            const int rl = lane ^ ((lane >> 3) & 7);   // swizzled read slot
            #pragma unroll
            for (int kk = 0; kk < 8; ++kk) {
                short8 bf[4];
                #pragma unroll
                for (int ct = 0; ct < 4; ++ct)
                    bf[ct] = Bp[(kk*16 + wave*4 + ct)*64 + lane];        // coalesced dwordx4 (L2-hot)
                #pragma unroll
                for (int rt = 0; rt < RT_N; ++rt) {
                    short8 af = ((const short8*)Xl4)[(rt*8 + kk)*64 + rl]; // ds_read_b128, conflict-free
                    #pragma unroll
                    for (int ct = 0; ct < 4; ++ct)
                        acc[rt][ct] = __builtin_amdgcn_mfma_f32_16x16x32_bf16(af, bf[ct], acc[rt][ct], 0, 0, 0);
                }
            }
            __syncthreads();   // all waves done reading X -> safe to overwrite

            // epilogue: bias+ReLU on primal rows; mask tangent rows; write back in A-frag order
            const int mcol = lane & 15;
            const int quad = lane >> 4;
            #pragma unroll
            for (int ct = 0; ct < 4; ++ct) {
                int n    = wave*64 + ct*16 + mcol;     // output column = next layer's k
                float bv = bias[n];
                int kkx = n >> 5;
                int qx  = (n >> 3) & 3;
                int jx  = n & 7;
                #pragma unroll
                for (int g = 0; g < 2; ++g) {
                    #pragma unroll
                    for (int r = 0; r < 4; ++r) {
                        float pre = acc[g][ct][r] + bv;
                        bool  mk  = pre > 0.0f;
                        float hv  = mk ? pre : 0.0f;
                        float tav = mk ? acc[2+g][ct][r] : 0.0f;
                        float tbv = mk ? acc[4+g][ct][r] : 0.0f;
                        int rowm = quad*4 + r;
                        int le   = qx*16 + rowm;
                        int scl  = le ^ ((le >> 3) & 7);
                        int eidx = ((g*8 + kkx)*64 + scl)*8 + jx;   // rt stride = 4096 elems
                        Xs[eidx]            = f2bf(hv);
                        Xs[eidx + 2*4096]   = f2bf(tav);
                        Xs[eidx + 4*4096]   = f2bf(tbv);
                    }
                }
            }
            __syncthreads();
        }

        // ---------------- layer 4: 256 -> 2 (VALU) + 2x2 Jacobian power series ----------------
        const float2* Wo2 = (const float2*)(Wo + (size_t)b * H * 2);
        const float*  bob = bo + (size_t)b * 2;
        {
            int s = tid >> 3, t = tid & 7;     // 32 samples x 8 k-slices (k = t*32 .. t*32+31)
            int m = s & 15, rh = s >> 4;
            float sh0=0, sh1=0, sa0=0, sa1=0, sb0=0, sb1=0;
            #pragma unroll
            for (int q = 0; q < 4; ++q) {
                int l  = q*16 + m;
                int cl = l ^ ((l >> 3) & 7);
                #pragma unroll
                for (int st = 0; st < 3; ++st) {
                    int rt = st*2 + rh;
                    uint4 raw = Xl4[(rt*8 + t)*64 + cl];
                    unsigned int ws[4] = {raw.x, raw.y, raw.z, raw.w};
                    #pragma unroll
                    for (int jj = 0; jj < 4; ++jj) {
                        #pragma unroll
                        for (int hh = 0; hh < 2; ++hh) {
                            float hv = bf2f((unsigned short)((ws[jj] >> (16*hh)) & 0xFFFFu));
                            int k = t*32 + q*8 + 2*jj + hh;
                            float2 wo = Wo2[k];
                            if (st == 0)      { sh0 = fmaf(hv, wo.x, sh0); sh1 = fmaf(hv, wo.y, sh1); }
                            else if (st == 1) { sa0 = fmaf(hv, wo.x, sa0); sa1 = fmaf(hv, wo.y, sa1); }
                            else              { sb0 = fmaf(hv, wo.x, sb0); sb1 = fmaf(hv, wo.y, sb1); }
                        }
                    }
                }
            }
            __syncthreads();                    // X reads done -> overlay partials
            float* pp = part + (size_t)tid * 6;
            pp[0]=sh0; pp[1]=sh1; pp[2]=sa0; pp[3]=sa1; pp[4]=sb0; pp[5]=sb1;
        }
        __syncthreads();
        if (tid < MS) {
            float SH0=0,SH1=0,SA0=0,SA1=0,SB0=0,SB1=0;
            #pragma unroll
            for (int t = 0; t < 8; ++t) {
                const float* pp = part + (size_t)(tid*8 + t) * 6;
                SH0+=pp[0]; SH1+=pp[1]; SA0+=pp[2]; SA1+=pp[3]; SB0+=pp[4]; SB1+=pp[5];
            }
            float pre0 = SH0 + bob[0], pre1 = SH1 + bob[1];
            bool  m0 = pre0 > 0.f,     m1 = pre1 > 0.f;
            float gx0 = m0 ? pre0 : 0.f, gx1 = m1 ? pre1 : 0.f;
            float J00 = m0 ? SA0 : 0.f;   // dg0/dx0
            float J01 = m0 ? SB0 : 0.f;   // dg0/dx1
            float J10 = m1 ? SA1 : 0.f;
            float J11 = m1 ? SB1 : 0.f;
            float v0 = vbuf[tid*2+0], v1 = vbuf[tid*2+1];
            float w0 = v0, w1 = v1, ld = 0.f;
            const float coef[5] = {1.f, -0.5f, 1.f/3.f, -0.25f, 0.2f};
            #pragma unroll
            for (int k = 0; k < 5; ++k) {
                float nw0 = fmaf(J00, w0, J01 * w1);
                float nw1 = fmaf(J10, w0, J11 * w1);
                w0 = nw0; w1 = nw1;
                ld = fmaf(coef[k], fmaf(w0, v0, w1 * v1), ld);
            }
            zbuf[tid*2+0] += gx0;
            zbuf[tid*2+1] += gx1;
            dlp -= ld;
        }
        __syncthreads();
    }

    if (tid < MS) {
        out[(size_t)(s0+tid)*2+0] = zbuf[tid*2+0];
        out[(size_t)(s0+tid)*2+1] = zbuf[tid*2+1];
        out[(size_t)2*BATCH + s0 + tid] = dlp;
    }
}

extern "C" void kernel_launch(void* const* d_in, const int* in_sizes, int n_in,
                              void* d_out, int out_size, void* d_ws, size_t ws_size,
                              hipStream_t stream) {
    const float* x  = (const float*)d_in[0];
    const float* v  = (const float*)d_in[1];
    const float* Wi = (const float*)d_in[2];
    const float* bi = (const float*)d_in[3];
    const float* Wm = (const float*)d_in[4];
    const float* bm = (const float*)d_in[5];
    const float* Wo = (const float*)d_in[6];
    const float* bo = (const float*)d_in[7];
    unsigned short* Wp = (unsigned short*)d_ws;   // needs 24*65536*2 = 3 MiB

    int nchunks = NBLK * NMID * 8192;
    pack_w_kernel<<<(nchunks + 255) / 256, 256, 0, stream>>>(Wm, Wp);
    flow_kernel<<<BATCH / MS, NT, 0, stream>>>(x, v, Wi, bi, bm, Wo, bo, Wp, (float*)d_out);
}

// Round 2
// 1655.353 us; speedup vs baseline: 1.5511x; 1.5511x over previous
//
#include <hip/hip_runtime.h>
#include <hip/hip_bf16.h>

#define BATCH 131072
#define H 256
#define NBLK 8
#define NMID 3
#define MS 32            // samples per workgroup
#define RT_N 6           // (3 streams * MS) / 16 row-tiles
#define NT 256           // threads per workgroup

typedef __attribute__((ext_vector_type(8))) short short8;   // 8 bf16 = 4 VGPRs (MFMA A/B frag)
typedef __attribute__((ext_vector_type(4))) float f32x4;    // MFMA C/D frag

__device__ __forceinline__ unsigned short f2bf(float f) {
    unsigned u = __float_as_uint(f);
    u += 0x7FFFu + ((u >> 16) & 1u);          // RNE; inputs are finite, no NaN handling needed
    return (unsigned short)(u >> 16);
}
__device__ __forceinline__ float bf2f(unsigned short b) {
    return __uint_as_float(((unsigned)b) << 16);
}

// Pack Wm (NB*NMID layers of [256][256] fp32, k-major) into MFMA B-fragment order bf16:
// chunk o serves (layer, kk, ct, lane); element j is k = kk*32 + (lane>>4)*8 + j, n = ct*16 + (lane&15).
__global__ void pack_w_kernel(const float* __restrict__ Wm, unsigned short* __restrict__ Wp) {
    int o = blockIdx.x * blockDim.x + threadIdx.x;   // 24 * 8192 chunks
    if (o >= NBLK * NMID * 8192) return;
    int lane  = o & 63;
    int ct    = (o >> 6) & 15;
    int kk    = (o >> 10) & 7;
    int layer = o >> 13;
    int n  = ct * 16 + (lane & 15);
    int k0 = kk * 32 + (lane >> 4) * 8;
    const float* src = Wm + (size_t)layer * H * H;
    unsigned int w[4];
    #pragma unroll
    for (int jj = 0; jj < 4; ++jj) {
        unsigned short a = f2bf(src[(size_t)(k0 + 2*jj    ) * H + n]);
        unsigned short b = f2bf(src[(size_t)(k0 + 2*jj + 1) * H + n]);
        w[jj] = (unsigned)a | ((unsigned)b << 16);
    }
    uint4 val; val.x = w[0]; val.y = w[1]; val.z = w[2]; val.w = w[3];
    ((uint4*)Wp)[o] = val;
}

// Fused flow kernel. Each workgroup owns 32 samples through all 8 i-ResBlocks.
// LDS X buffer holds [6 row-tiles][8 kk][64 chunk-slots][8 bf16] in A-fragment order,
// with chunk-slot swizzle sigma(l) = l ^ ((l>>3)&7) (involution; kills epilogue-write bank conflicts).
// launch_bounds(256,2): 256-VGPR budget. acc tile = 96 regs; at (256,3) the 170-reg
// cap forced accumulator spills -> 6 GB HBM scratch traffic (R1: 2.2 GB WRITE_SIZE).
__global__ __launch_bounds__(NT, 2)
void flow_kernel(const float* __restrict__ x, const float* __restrict__ v,
                 const float* __restrict__ Wi, const float* __restrict__ bi,
                 const float* __restrict__ bm, const float* __restrict__ Wo,
                 const float* __restrict__ bo,
                 const unsigned short* __restrict__ Wp,
                 float* __restrict__ out)
{
    __shared__ uint4 Xl4[RT_N * 8 * 64];     // 3072 chunks * 16B = 48 KiB
    __shared__ float zbuf[MS * 2];
    __shared__ float vbuf[MS * 2];

    unsigned short* Xs = (unsigned short*)Xl4;
    float* part = (float*)Xl4;               // layer-4 partial overlay (6 KiB, X is dead then)

    const int tid  = threadIdx.x;
    const int wave = tid >> 6;
    const int lane = tid & 63;
    const int s0   = blockIdx.x * MS;

    float dlp = 0.0f;
    if (tid < MS) {
        zbuf[tid*2+0] = x[(size_t)(s0+tid)*2+0];
        zbuf[tid*2+1] = x[(size_t)(s0+tid)*2+1];
        vbuf[tid*2+0] = v[(size_t)(s0+tid)*2+0];
        vbuf[tid*2+1] = v[(size_t)(s0+tid)*2+1];
    }
    __syncthreads();

    for (int b = 0; b < NBLK; ++b) {
        // ---------------- layer 0: 2 -> 256 (VALU), fill X in A-frag order ----------------
        const float* Wi0 = Wi + (size_t)b * 2 * H;
        const float* Wi1 = Wi0 + H;
        const float* bib = bi + (size_t)b * H;
        #pragma unroll
        for (int cc = 0; cc < (RT_N*8*64)/NT; ++cc) {
            int c  = cc * NT + tid;           // global chunk index
            int cl = c & 63;                  // stored slot within (rt,kk) group
            int kk = (c >> 6) & 7;
            int rt = c >> 9;
            int l  = cl ^ ((cl >> 3) & 7);    // serving lane (sigma involution)
            int m  = l & 15, q = l >> 4;
            int s  = ((rt & 1) << 4) | m;     // sample within wg
            int stream = rt >> 1;             // 0=h, 1=ta(e0), 2=tb(e1)
            float z0 = zbuf[s*2+0], z1 = zbuf[s*2+1];
            int nb = kk * 32 + q * 8;
            unsigned int wv[4];
            #pragma unroll
            for (int jj = 0; jj < 4; ++jj) {
                unsigned int pr = 0;
                #pragma unroll
                for (int hh = 0; hh < 2; ++hh) {
                    int n = nb + 2*jj + hh;
                    float w0 = Wi0[n], w1 = Wi1[n];
                    float pre = fmaf(z0, w0, fmaf(z1, w1, bib[n]));
                    float o;
                    if (stream == 0)      o = fmaxf(pre, 0.0f);
                    else if (stream == 1) o = (pre > 0.0f) ? w0 : 0.0f;   // (e0 @ Wi) * mask
                    else                  o = (pre > 0.0f) ? w1 : 0.0f;   // (e1 @ Wi) * mask
                    pr |= ((unsigned)f2bf(o)) << (16 * hh);
                }
                wv[jj] = pr;
            }
            uint4 pk; pk.x = wv[0]; pk.y = wv[1]; pk.z = wv[2]; pk.w = wv[3];
            Xl4[c] = pk;
        }
        __syncthreads();

        // ---------------- mid layers: 3x (256 -> 256) via MFMA ----------------
        for (int li = 0; li < NMID; ++li) {
            const int layer = b * NMID + li;
            const short8* Bp  = ((const short8*)Wp) + (size_t)layer * 8192;
            const float* bias = bm + (size_t)layer * H;

            f32x4 acc[RT_N][4];
            #pragma unroll
            for (int rt = 0; rt < RT_N; ++rt)
                #pragma unroll
                for (int ct = 0; ct < 4; ++ct)
                    acc[rt][ct] = (f32x4){0.f, 0.f, 0.f, 0.f};

            const int rl = lane ^ ((lane >> 3) & 7);   // swizzled read slot
            #pragma unroll
            for (int kk = 0; kk < 8; ++kk) {
                short8 bf[4];
                #pragma unroll
                for (int ct = 0; ct < 4; ++ct)
                    bf[ct] = Bp[(kk*16 + wave*4 + ct)*64 + lane];        // coalesced dwordx4 (L2-hot)
                #pragma unroll
                for (int rt = 0; rt < RT_N; ++rt) {
                    short8 af = ((const short8*)Xl4)[(rt*8 + kk)*64 + rl]; // ds_read_b128, conflict-free
                    #pragma unroll
                    for (int ct = 0; ct < 4; ++ct)
                        acc[rt][ct] = __builtin_amdgcn_mfma_f32_16x16x32_bf16(af, bf[ct], acc[rt][ct], 0, 0, 0);
                }
            }
            __syncthreads();   // all waves done reading X -> safe to overwrite

            // epilogue: bias+ReLU on primal rows; mask tangent rows; write back in A-frag order
            const int mcol = lane & 15;
            const int quad = lane >> 4;
            #pragma unroll
            for (int ct = 0; ct < 4; ++ct) {
                int n    = wave*64 + ct*16 + mcol;     // output column = next layer's k
                float bv = bias[n];
                int kkx = n >> 5;
                int qx  = (n >> 3) & 3;
                int jx  = n & 7;
                #pragma unroll
                for (int g = 0; g < 2; ++g) {
                    #pragma unroll
                    for (int r = 0; r < 4; ++r) {
                        float pre = acc[g][ct][r] + bv;
                        bool  mk  = pre > 0.0f;
                        float hv  = mk ? pre : 0.0f;
                        float tav = mk ? acc[2+g][ct][r] : 0.0f;
                        float tbv = mk ? acc[4+g][ct][r] : 0.0f;
                        int rowm = quad*4 + r;
                        int le   = qx*16 + rowm;
                        int scl  = le ^ ((le >> 3) & 7);
                        int eidx = ((g*8 + kkx)*64 + scl)*8 + jx;   // rt stride = 4096 elems
                        Xs[eidx]            = f2bf(hv);
                        Xs[eidx + 2*4096]   = f2bf(tav);
                        Xs[eidx + 4*4096]   = f2bf(tbv);
                    }
                }
            }
            __syncthreads();
        }

        // ---------------- layer 4: 256 -> 2 (VALU) + 2x2 Jacobian power series ----------------
        const float2* Wo2 = (const float2*)(Wo + (size_t)b * H * 2);
        const float*  bob = bo + (size_t)b * 2;
        {
            int s = tid >> 3, t = tid & 7;     // 32 samples x 8 k-slices (k = t*32 .. t*32+31)
            int m = s & 15, rh = s >> 4;
            float sh0=0, sh1=0, sa0=0, sa1=0, sb0=0, sb1=0;
            #pragma unroll
            for (int q = 0; q < 4; ++q) {
                int l  = q*16 + m;
                int cl = l ^ ((l >> 3) & 7);
                #pragma unroll
                for (int st = 0; st < 3; ++st) {
                    int rt = st*2 + rh;
                    uint4 raw = Xl4[(rt*8 + t)*64 + cl];
                    unsigned int ws[4] = {raw.x, raw.y, raw.z, raw.w};
                    #pragma unroll
                    for (int jj = 0; jj < 4; ++jj) {
                        #pragma unroll
                        for (int hh = 0; hh < 2; ++hh) {
                            float hv = bf2f((unsigned short)((ws[jj] >> (16*hh)) & 0xFFFFu));
                            int k = t*32 + q*8 + 2*jj + hh;
                            float2 wo = Wo2[k];
                            if (st == 0)      { sh0 = fmaf(hv, wo.x, sh0); sh1 = fmaf(hv, wo.y, sh1); }
                            else if (st == 1) { sa0 = fmaf(hv, wo.x, sa0); sa1 = fmaf(hv, wo.y, sa1); }
                            else              { sb0 = fmaf(hv, wo.x, sb0); sb1 = fmaf(hv, wo.y, sb1); }
                        }
                    }
                }
            }
            __syncthreads();                    // X reads done -> overlay partials
            float* pp = part + (size_t)tid * 6;
            pp[0]=sh0; pp[1]=sh1; pp[2]=sa0; pp[3]=sa1; pp[4]=sb0; pp[5]=sb1;
        }
        __syncthreads();
        if (tid < MS) {
            float SH0=0,SH1=0,SA0=0,SA1=0,SB0=0,SB1=0;
            #pragma unroll
            for (int t = 0; t < 8; ++t) {
                const float* pp = part + (size_t)(tid*8 + t) * 6;
                SH0+=pp[0]; SH1+=pp[1]; SA0+=pp[2]; SA1+=pp[3]; SB0+=pp[4]; SB1+=pp[5];
            }
            float pre0 = SH0 + bob[0], pre1 = SH1 + bob[1];
            bool  m0 = pre0 > 0.f,     m1 = pre1 > 0.f;
            float gx0 = m0 ? pre0 : 0.f, gx1 = m1 ? pre1 : 0.f;
            float J00 = m0 ? SA0 : 0.f;   // dg0/dx0
            float J01 = m0 ? SB0 : 0.f;   // dg0/dx1
            float J10 = m1 ? SA1 : 0.f;
            float J11 = m1 ? SB1 : 0.f;
            float v0 = vbuf[tid*2+0], v1 = vbuf[tid*2+1];
            float w0 = v0, w1 = v1, ld = 0.f;
            const float coef[5] = {1.f, -0.5f, 1.f/3.f, -0.25f, 0.2f};
            #pragma unroll
            for (int k = 0; k < 5; ++k) {
                float nw0 = fmaf(J00, w0, J01 * w1);
                float nw1 = fmaf(J10, w0, J11 * w1);
                w0 = nw0; w1 = nw1;
                ld = fmaf(coef[k], fmaf(w0, v0, w1 * v1), ld);
            }
            zbuf[tid*2+0] += gx0;
            zbuf[tid*2+1] += gx1;
            dlp -= ld;
        }
        __syncthreads();
    }

    if (tid < MS) {
        out[(size_t)(s0+tid)*2+0] = zbuf[tid*2+0];
        out[(size_t)(s0+tid)*2+1] = zbuf[tid*2+1];
        out[(size_t)2*BATCH + s0 + tid] = dlp;
    }
}

extern "C" void kernel_launch(void* const* d_in, const int* in_sizes, int n_in,
                              void* d_out, int out_size, void* d_ws, size_t ws_size,
                              hipStream_t stream) {
    const float* x  = (const float*)d_in[0];
    const float* v  = (const float*)d_in[1];
    const float* Wi = (const float*)d_in[2];
    const float* bi = (const float*)d_in[3];
    const float* Wm = (const float*)d_in[4];
    const float* bm = (const float*)d_in[5];
    const float* Wo = (const float*)d_in[6];
    const float* bo = (const float*)d_in[7];
    unsigned short* Wp = (unsigned short*)d_ws;   // needs 24*65536*2 = 3 MiB

    int nchunks = NBLK * NMID * 8192;
    pack_w_kernel<<<(nchunks + 255) / 256, 256, 0, stream>>>(Wm, Wp);
    flow_kernel<<<BATCH / MS, NT, 0, stream>>>(x, v, Wi, bi, bm, Wo, bo, Wp, (float*)d_out);
}

// Round 3
// 1261.034 us; speedup vs baseline: 2.0361x; 1.3127x over previous
//
#include <hip/hip_runtime.h>
#include <hip/hip_bf16.h>

#define BATCH 131072
#define H 256
#define NBLK 8
#define NMID 3
#define MS 32            // samples per workgroup
#define RT_N 6           // (3 streams * MS) / 16 row-tiles
#define NT 256           // threads per workgroup

typedef __attribute__((ext_vector_type(8))) short short8;   // 8 bf16 = 4 VGPRs (MFMA A/B frag)
typedef __attribute__((ext_vector_type(4))) float f32x4;    // MFMA C/D frag

// pack two f32 -> two bf16 (round-half-up) in 3 VALU ops: 2 adds + v_perm.
// low16 = bf(a), high16 = bf(b)  (matches (bf(a) | bf(b)<<16))
__device__ __forceinline__ unsigned pk2(float a, float b) {
    unsigned ua = __float_as_uint(a) + 0x8000u;
    unsigned ub = __float_as_uint(b) + 0x8000u;
    return __builtin_amdgcn_perm(ub, ua, 0x07060302u);
}
__device__ __forceinline__ unsigned short f2bf(float f) {
    return (unsigned short)((__float_as_uint(f) + 0x8000u) >> 16);
}

// Pack Wm into MFMA B-frag order bf16 with COLUMN-PERMUTED tiles:
// tile T = wave*4+ct covers physical cols n = (T>>2)*64 + m*4 + (T&3), m = lane&15.
// => in the epilogue each thread owns 4 consecutive columns (one ds_write_b64).
__global__ void pack_w_kernel(const float* __restrict__ Wm, unsigned short* __restrict__ Wp) {
    int o = blockIdx.x * blockDim.x + threadIdx.x;   // 24 * 8192 chunks
    if (o >= NBLK * NMID * 8192) return;
    int lane  = o & 63;
    int T     = (o >> 6) & 15;
    int kk    = (o >> 10) & 7;
    int layer = o >> 13;
    int n  = (T >> 2) * 64 + (lane & 15) * 4 + (T & 3);
    int k0 = kk * 32 + (lane >> 4) * 8;
    const float* src = Wm + (size_t)layer * H * H;
    unsigned int w[4];
    #pragma unroll
    for (int jj = 0; jj < 4; ++jj)
        w[jj] = pk2(src[(size_t)(k0 + 2*jj) * H + n], src[(size_t)(k0 + 2*jj + 1) * H + n]);
    uint4 val; val.x = w[0]; val.y = w[1]; val.z = w[2]; val.w = w[3];
    ((uint4*)Wp)[o] = val;
}

// bias+ReLU on primal, mask tangents, write next layer's A-frag X (b64 stores).
__device__ __forceinline__ void epilogue_write(const f32x4 (&acc)[RT_N][4],
                                               const float* __restrict__ bias,
                                               unsigned short* __restrict__ Xs,
                                               int wave, int lane) {
    const int mcol = lane & 15, quad = lane >> 4;
    const int nb = wave * 64 + mcol * 4;           // 4 consecutive output cols
    const float4 bv = *(const float4*)(bias + nb);
    const int kkx = nb >> 5;
    const int qx  = (nb >> 3) & 3;
    const int jb  = nb & 7;                        // 0 or 4
    #pragma unroll
    for (int g = 0; g < 2; ++g) {
        #pragma unroll
        for (int r = 0; r < 4; ++r) {
            float pre[4], hv[4], ta[4], tb[4];
            pre[0] = acc[g][0][r] + bv.x; pre[1] = acc[g][1][r] + bv.y;
            pre[2] = acc[g][2][r] + bv.z; pre[3] = acc[g][3][r] + bv.w;
            #pragma unroll
            for (int c = 0; c < 4; ++c) {
                bool mk = pre[c] > 0.0f;
                hv[c] = mk ? pre[c]        : 0.0f;
                ta[c] = mk ? acc[2+g][c][r] : 0.0f;
                tb[c] = mk ? acc[4+g][c][r] : 0.0f;
            }
            int rowm = quad * 4 + r;
            int le   = qx * 16 + rowm;
            int scl  = le ^ ((le >> 3) & 7);
            int e0   = (((g * 8 + kkx) * 64 + scl) * 8) + jb;
            uint2 ph; ph.x = pk2(hv[0], hv[1]); ph.y = pk2(hv[2], hv[3]);
            uint2 pa; pa.x = pk2(ta[0], ta[1]); pa.y = pk2(ta[2], ta[3]);
            uint2 pb; pb.x = pk2(tb[0], tb[1]); pb.y = pk2(tb[2], tb[3]);
            *(uint2*)(Xs + e0)          = ph;
            *(uint2*)(Xs + e0 + 8192)   = pa;   // ta rows: rt offset +2 => +2*8*64*8 elems
            *(uint2*)(Xs + e0 + 16384)  = pb;   // tb rows: rt offset +4
        }
    }
}

__global__ __launch_bounds__(NT, 2)
void flow_kernel(const float* __restrict__ x, const float* __restrict__ v,
                 const float* __restrict__ Wi, const float* __restrict__ bi,
                 const float* __restrict__ bm, const float* __restrict__ Wo,
                 const float* __restrict__ bo,
                 const unsigned short* __restrict__ Wp,
                 float* __restrict__ out)
{
    __shared__ uint4 Xl4[RT_N * 8 * 64];     // 3072 chunks * 16B = 48 KiB
    __shared__ float zbuf[MS * 2];
    __shared__ float vbuf[MS * 2];

    unsigned short* Xs = (unsigned short*)Xl4;

    const int tid  = threadIdx.x;
    const int wave = tid >> 6;
    const int lane = tid & 63;
    const int mcol = lane & 15;
    const int quad = lane >> 4;
    const int s0   = blockIdx.x * MS;
    const int rl   = lane ^ ((lane >> 3) & 7);   // swizzled A-read slot

    float dlp = 0.0f;
    if (tid < MS) {
        zbuf[tid*2+0] = x[(size_t)(s0+tid)*2+0];
        zbuf[tid*2+1] = x[(size_t)(s0+tid)*2+1];
        vbuf[tid*2+0] = v[(size_t)(s0+tid)*2+0];
        vbuf[tid*2+1] = v[(size_t)(s0+tid)*2+1];
    }
    __syncthreads();

    for (int b = 0; b < NBLK; ++b) {
        // ------------- layer 0: 2 -> 256 via MFMA (K padded to 32) -------------
        // Fill X0: rows 96 x K32, chunks at (rt*8+0)*64 + slot; only q==0,j<2 nonzero.
        #pragma unroll
        for (int cc = 0; cc < 2; ++cc) {
            int c = cc * NT + tid;
            if (c < 384) {
                int rt = c >> 6, cl = c & 63;
                int l = cl ^ ((cl >> 3) & 7);
                int m = l & 15, q = l >> 4;
                int st = rt >> 1;
                uint4 pk = {0u, 0u, 0u, 0u};
                if (q == 0) {
                    if (st == 0) {
                        int s = ((rt & 1) << 4) | m;
                        pk.x = pk2(zbuf[s*2+0], zbuf[s*2+1]);
                    } else if (st == 1) pk.x = 0x00003F80u;   // (1,0)
                    else                pk.x = 0x3F800000u;   // (0,1)
                }
                Xl4[rt * 512 + cl] = pk;
            }
        }
        __syncthreads();

        const float* Wi0 = Wi + (size_t)b * 2 * H;
        const float* Wi1 = Wi0 + H;
        {
            short8 b0[4];
            #pragma unroll
            for (int ct = 0; ct < 4; ++ct) {
                short8 z = {0,0,0,0,0,0,0,0};
                if (lane < 16) {
                    int n = wave * 64 + lane * 4 + ct;
                    unsigned p = pk2(Wi0[n], Wi1[n]);
                    z[0] = (short)(p & 0xFFFFu);
                    z[1] = (short)(p >> 16);
                }
                b0[ct] = z;
            }
            f32x4 acc[RT_N][4];
            #pragma unroll
            for (int rt = 0; rt < RT_N; ++rt)
                #pragma unroll
                for (int ct = 0; ct < 4; ++ct)
                    acc[rt][ct] = (f32x4){0.f, 0.f, 0.f, 0.f};
            #pragma unroll
            for (int rt = 0; rt < RT_N; ++rt) {
                short8 af = ((const short8*)Xl4)[(rt * 8) * 64 + rl];
                #pragma unroll
                for (int ct = 0; ct < 4; ++ct)
                    acc[rt][ct] = __builtin_amdgcn_mfma_f32_16x16x32_bf16(af, b0[ct], acc[rt][ct], 0, 0, 0);
            }
            __syncthreads();                     // X0 reads done
            epilogue_write(acc, bi + (size_t)b * H, Xs, wave, lane);
            __syncthreads();
        }

        // ------------- mid layers: 3x (256 -> 256) via MFMA -------------
        for (int li = 0; li < NMID; ++li) {
            const int layer = b * NMID + li;
            const short8* Bp  = ((const short8*)Wp) + (size_t)layer * 8192;
            const float* bias = bm + (size_t)layer * H;

            f32x4 acc[RT_N][4];
            #pragma unroll
            for (int rt = 0; rt < RT_N; ++rt)
                #pragma unroll
                for (int ct = 0; ct < 4; ++ct)
                    acc[rt][ct] = (f32x4){0.f, 0.f, 0.f, 0.f};

            #pragma unroll
            for (int kk = 0; kk < 8; ++kk) {
                short8 bf[4];
                #pragma unroll
                for (int ct = 0; ct < 4; ++ct)
                    bf[ct] = Bp[(kk*16 + wave*4 + ct)*64 + lane];        // coalesced b128 (L2-hot)
                #pragma unroll
                for (int rt = 0; rt < RT_N; ++rt) {
                    short8 af = ((const short8*)Xl4)[(rt*8 + kk)*64 + rl]; // ds_read_b128
                    #pragma unroll
                    for (int ct = 0; ct < 4; ++ct)
                        acc[rt][ct] = __builtin_amdgcn_mfma_f32_16x16x32_bf16(af, bf[ct], acc[rt][ct], 0, 0, 0);
                }
            }
            __syncthreads();                     // all waves done reading X
            epilogue_write(acc, bias, Xs, wave, lane);
            __syncthreads();
        }

        // ------------- layer 4: 256 -> 2 via MFMA (N padded to 16) -------------
        const float* Wob = Wo + (size_t)b * H * 2;
        const float* bob = bo + (size_t)b * 2;
        {
            short8 b4[2];
            #pragma unroll
            for (int kki = 0; kki < 2; ++kki) {
                short8 z = {0,0,0,0,0,0,0,0};
                if (mcol < 2) {
                    int kb = (wave * 2 + kki) * 32 + quad * 8;
                    #pragma unroll
                    for (int jj = 0; jj < 4; ++jj) {
                        unsigned p = pk2(Wob[(kb + 2*jj) * 2 + mcol], Wob[(kb + 2*jj + 1) * 2 + mcol]);
                        z[2*jj]   = (short)(p & 0xFFFFu);
                        z[2*jj+1] = (short)(p >> 16);
                    }
                }
                b4[kki] = z;
            }
            f32x4 accL[RT_N];
            #pragma unroll
            for (int rt = 0; rt < RT_N; ++rt) accL[rt] = (f32x4){0.f, 0.f, 0.f, 0.f};
            #pragma unroll
            for (int rt = 0; rt < RT_N; ++rt) {
                short8 a0 = ((const short8*)Xl4)[(rt*8 + wave*2    )*64 + rl];
                accL[rt] = __builtin_amdgcn_mfma_f32_16x16x32_bf16(a0, b4[0], accL[rt], 0, 0, 0);
                short8 a1 = ((const short8*)Xl4)[(rt*8 + wave*2 + 1)*64 + rl];
                accL[rt] = __builtin_amdgcn_mfma_f32_16x16x32_bf16(a1, b4[1], accL[rt], 0, 0, 0);
            }
            __syncthreads();                     // X dead; overlay partials
            float* part = (float*)Xl4;           // 768 floats
            if (mcol < 2) {
                #pragma unroll
                for (int rt = 0; rt < RT_N; ++rt)
                    #pragma unroll
                    for (int r = 0; r < 4; ++r)
                        part[((rt*16 + quad*4 + r)*2 + mcol)*4 + wave] = accL[rt][r];
            }
            __syncthreads();
            float* res = part + 768;             // 192 floats
            if (tid < 192) {
                float4 p4 = ((const float4*)part)[tid];
                res[tid] = p4.x + p4.y + p4.z + p4.w;
            }
            __syncthreads();
            if (tid < MS) {
                int g = tid >> 4, row = tid & 15;
                // res index: ((st*2+g)*16 + row)*2 + m
                int base = (g * 16 + row) * 2;
                float SH0 = res[base], SH1 = res[base + 1];
                float SA0 = res[base + 64], SA1 = res[base + 65];   // st=1: +2*16*2
                float SB0 = res[base + 128], SB1 = res[base + 129]; // st=2
                float pre0 = SH0 + bob[0], pre1 = SH1 + bob[1];
                bool  m0 = pre0 > 0.f,     m1 = pre1 > 0.f;
                float gx0 = m0 ? pre0 : 0.f, gx1 = m1 ? pre1 : 0.f;
                float J00 = m0 ? SA0 : 0.f;
                float J01 = m0 ? SB0 : 0.f;
                float J10 = m1 ? SA1 : 0.f;
                float J11 = m1 ? SB1 : 0.f;
                float v0 = vbuf[tid*2+0], v1 = vbuf[tid*2+1];
                float w0 = v0, w1 = v1, ld = 0.f;
                const float coef[5] = {1.f, -0.5f, 1.f/3.f, -0.25f, 0.2f};
                #pragma unroll
                for (int k = 0; k < 5; ++k) {
                    float nw0 = fmaf(J00, w0, J01 * w1);
                    float nw1 = fmaf(J10, w0, J11 * w1);
                    w0 = nw0; w1 = nw1;
                    ld = fmaf(coef[k], fmaf(w0, v0, w1 * v1), ld);
                }
                zbuf[tid*2+0] += gx0;
                zbuf[tid*2+1] += gx1;
                dlp -= ld;
            }
        }
        __syncthreads();
    }

    if (tid < MS) {
        out[(size_t)(s0+tid)*2+0] = zbuf[tid*2+0];
        out[(size_t)(s0+tid)*2+1] = zbuf[tid*2+1];
        out[(size_t)2*BATCH + s0 + tid] = dlp;
    }
}

extern "C" void kernel_launch(void* const* d_in, const int* in_sizes, int n_in,
                              void* d_out, int out_size, void* d_ws, size_t ws_size,
                              hipStream_t stream) {
    const float* x  = (const float*)d_in[0];
    const float* v  = (const float*)d_in[1];
    const float* Wi = (const float*)d_in[2];
    const float* bi = (const float*)d_in[3];
    const float* Wm = (const float*)d_in[4];
    const float* bm = (const float*)d_in[5];
    const float* Wo = (const float*)d_in[6];
    const float* bo = (const float*)d_in[7];
    unsigned short* Wp = (unsigned short*)d_ws;   // 24*65536*2 = 3 MiB

    int nchunks = NBLK * NMID * 8192;
    pack_w_kernel<<<(nchunks + 255) / 256, 256, 0, stream>>>(Wm, Wp);
    flow_kernel<<<BATCH / MS, NT, 0, stream>>>(x, v, Wi, bi, bm, Wo, bo, Wp, (float*)d_out);
}